// Round 3
// baseline (309.283 us; speedup 1.0000x reference)
//
#include <hip/hip_runtime.h>
#include <hip/hip_bf16.h>

#define ACT 14
#define CC 128
#define HH 256
#define EPB 182                 // edges per batch (14*13)
#define NB 2048
#define M2 (NB*EPB)             // 372736 edge-rows
#define NODES (NB*ACT)          // 28672
#define LP_CONST (-182.0f * 0.91893853320467274f)   // -E*0.5*ln(2pi)

typedef short s16x8 __attribute__((ext_vector_type(8)));
typedef float f32x4 __attribute__((ext_vector_type(4)));

__device__ __forceinline__ short f2bf(float f) {
    unsigned u = __float_as_uint(f);
    unsigned r = (u + 0x7fffu + ((u >> 16) & 1u)) >> 16;   // RNE
    return (short)r;
}
__device__ __forceinline__ float leaky(float x) { return fmaxf(x, 0.01f * x); }
__device__ __forceinline__ float softplusf(float x) { return x > 15.f ? x : log1pf(expf(x)); }

union bf2u { __hip_bfloat162 h; int i; short s[2]; };
__device__ __forceinline__ int pk_bf16(float a, float b) {
    bf2u u; u.h = __float22bfloat162_rn(make_float2(a, b));
    return u.i;
}

// ---------------------------------------------------------------------------
// Kernel 0 (prep): weight transposes / bf16 pre-conversions (one-time, tiny)
// ---------------------------------------------------------------------------
__global__ __launch_bounds__(256) void prep_kernel(
    const float* __restrict__ conv_w, const float* __restrict__ lin1_w,
    const float* __restrict__ lin2_w, short* __restrict__ W2bf,
    short* __restrict__ W1bf, float* __restrict__ cwT, float* __restrict__ w1sT)
{
    int i = blockIdx.x * 256 + threadIdx.x;      // grid = 256 blocks -> 65536
    W2bf[i] = f2bf(lin2_w[i]);
    {
        int n = i >> 7, k = i & 127;
        float v = (n < 256) ? lin1_w[n * 256 + k] : lin1_w[(n - 256) * 256 + 128 + k];
        W1bf[i] = f2bf(v);
    }
    if (i < 16384) {
        int k = i >> 7, j = i & 127;
        cwT[i] = conv_w[j * 128 + k];
    }
    if (i < 32768) {
        int k = i >> 8, h = i & 255;
        w1sT[i] = lin1_w[h * 256 + k] + lin1_w[h * 256 + 128 + k];
    }
}

// ---------------------------------------------------------------------------
// Kernel 1: per-batch g = relu(cwT^T @ (ssum/14) + conv_b)
//           wvec[b] = w1sT^T @ g + lin1_b
// ---------------------------------------------------------------------------
#define BPB 4
__global__ __launch_bounds__(256) void gw_kernel(
    const float* __restrict__ state, const float* __restrict__ cwT,
    const float* __restrict__ conv_b, const float* __restrict__ w1sT,
    const float* __restrict__ lin1_b, float* __restrict__ wvec)
{
    __shared__ float ssum[BPB][CC];
    __shared__ float g[BPB][CC];
    const int t = threadIdx.x;
    const int b0 = blockIdx.x * BPB;

    #pragma unroll
    for (int it = 0; it < 2; ++it) {
        int idx = t + it * 256;
        int bb = idx >> 7, c = idx & 127;
        const float* sp = state + (size_t)(b0 + bb) * (ACT * CC) + c;
        float s = 0.f;
        #pragma unroll
        for (int i = 0; i < ACT; ++i) s += sp[i * CC];
        ssum[bb][c] = s * (1.f / 14.f);
    }
    __syncthreads();

    {
        int j = t & 127, half = t >> 7;
        float a0 = 0.f, a1 = 0.f;
        #pragma unroll 4
        for (int k = 0; k < CC; ++k) {
            float wv = cwT[k * CC + j];
            a0 += wv * ssum[half * 2 + 0][k];
            a1 += wv * ssum[half * 2 + 1][k];
        }
        float cb = conv_b[j];
        g[half * 2 + 0][j] = fmaxf(a0 + cb, 0.f);
        g[half * 2 + 1][j] = fmaxf(a1 + cb, 0.f);
    }
    __syncthreads();

    {
        float a[BPB] = {0.f, 0.f, 0.f, 0.f};
        #pragma unroll 4
        for (int k = 0; k < CC; ++k) {
            float wv = w1sT[k * HH + t];
            #pragma unroll
            for (int b = 0; b < BPB; ++b) a[b] += wv * g[b][k];
        }
        float lb = lin1_b[t];
        #pragma unroll
        for (int b = 0; b < BPB; ++b)
            wvec[(size_t)(b0 + b) * HH + t] = a[b] + lb;
    }
}

// ---------------------------------------------------------------------------
// Kernel 2: UV[node][0:256] = W1L @ state + w (folded), [256:512] = W1R @ state
// M=28672, K=128, N=512 (grid.y 2). B held fully in registers (16 frags).
// A double-buffered through LDS.
// ---------------------------------------------------------------------------
__global__ __launch_bounds__(512) void uv_gemm(
    const float* __restrict__ state, const short* __restrict__ W1bf,
    const float* __restrict__ wvec, short* __restrict__ UV)
{
    __shared__ short As[2][128 * 40];

    const int t = threadIdx.x;
    const int mbase = blockIdx.x * 128;
    const int ntile = blockIdx.y;
    const int lane = t & 63, ln = lane & 15, q = lane >> 4;
    const int wave = t >> 6, wy = wave >> 2, wx = wave & 3;

    // all 16 B-fragments in registers (K=128 -> 4 chunks x 4 col-frags)
    const short* bp = W1bf + (size_t)(ntile * 256 + wx * 64 + ln) * CC + q * 8;
    s16x8 bf_[4][4];
    #pragma unroll
    for (int kk = 0; kk < 4; ++kk)
        #pragma unroll
        for (int fc = 0; fc < 4; ++fc)
            bf_[kk][fc] = *(const s16x8*)(bp + fc * 16 * CC + kk * 32);

    f32x4 zero = {0.f, 0.f, 0.f, 0.f};
    f32x4 acc[4][4];
    #pragma unroll
    for (int i = 0; i < 4; ++i)
        #pragma unroll
        for (int j = 0; j < 4; ++j) acc[i][j] = zero;

    const int r = t >> 2, c8 = t & 3;
    const float* ap = state + (size_t)(mbase + r) * CC + c8 * 8;

    auto stage = [&](int kk, int buf) {
        f32x4 x0 = *(const f32x4*)(ap + kk * 32);
        f32x4 x1 = *(const f32x4*)(ap + kk * 32 + 4);
        int* dst = (int*)&As[buf][r * 40 + c8 * 8];
        dst[0] = pk_bf16(x0[0], x0[1]); dst[1] = pk_bf16(x0[2], x0[3]);
        dst[2] = pk_bf16(x1[0], x1[1]); dst[3] = pk_bf16(x1[2], x1[3]);
    };

    stage(0, 0);
    for (int kk = 0; kk < 4; ++kk) {
        int cur = kk & 1;
        __syncthreads();
        s16x8 af[4];
        #pragma unroll
        for (int fr = 0; fr < 4; ++fr)
            af[fr] = *(s16x8*)&As[cur][(wy * 64 + fr * 16 + ln) * 40 + q * 8];
        if (kk < 3) stage(kk + 1, cur ^ 1);
        #pragma unroll
        for (int fr = 0; fr < 4; ++fr)
            #pragma unroll
            for (int fc = 0; fc < 4; ++fc)
                acc[fr][fc] = __builtin_amdgcn_mfma_f32_16x16x32_bf16(af[fr], bf_[kk][fc], acc[fr][fc], 0, 0, 0);
    }

    // epilogue: fold w into u-half (ntile 0): u' = u + w
    #pragma unroll
    for (int fr = 0; fr < 4; ++fr)
        #pragma unroll
        for (int fc = 0; fc < 4; ++fc) {
            int col = wx * 64 + fc * 16 + ln;
            #pragma unroll
            for (int rg = 0; rg < 4; ++rg) {
                int m = mbase + wy * 64 + fr * 16 + q * 4 + rg;
                float v = acc[fr][fc][rg];
                if (ntile == 0) v += wvec[(size_t)(m / ACT) * HH + col];
                UV[(size_t)m * 512 + ntile * 256 + col] = f2bf(v);
            }
        }
}

// ---------------------------------------------------------------------------
// Kernel 3: fused edge GEMM, one block per batch (192-row padded M-tile,
// 768 threads = 12 waves in a 3x4 grid). Node data LDS-resident; A-fragments
// built per-lane from LDS (no staging, no K-loop barriers); B prefetched
// global->reg from L2-hot W2bf.
// ---------------------------------------------------------------------------
__global__ __launch_bounds__(768, 3) void edge_gemm(
    const short* __restrict__ UV, const short* __restrict__ W2bf,
    const float* __restrict__ lin2_b,
    const float* __restrict__ mu_w, const float* __restrict__ mu_b,
    const float* __restrict__ sig_w, const float* __restrict__ sig_b,
    const float* __restrict__ noise, const int* __restrict__ edges,
    float* __restrict__ out)
{
    __shared__ short nodeL[14 * 520];        // 520-short stride: conflict-free v-reads
    __shared__ float mu_acc[192], sg_acc[192];
    __shared__ float lp_acc;

    const int t = threadIdx.x;
    const int b = blockIdx.x;                 // batch
    const int lane = t & 63, ln = lane & 15, q = lane >> 4;
    const int wave = t >> 6;                  // 0..11
    const int wy = wave >> 2;                 // 0..2  (row group of 64)
    const int wx = wave & 3;                  // 0..3  (col group of 64)

    // ---- one-shot: 14 node rows (u'|v' = 512 shorts = 1024 B = 64 lanes x 16B)
    for (int n = wave; n < 14; n += 12) {
        const short* g = UV + ((size_t)(b * 14 + n)) * 512 + lane * 8;
        __builtin_amdgcn_global_load_lds(
            (const __attribute__((address_space(1))) void*)g,
            (__attribute__((address_space(3))) void*)&nodeL[n * 520],
            16, 0, 0);
    }
    if (t < 192) { mu_acc[t] = 0.f; sg_acc[t] = 0.f; }
    if (t == 0) lp_acc = 0.f;

    // per-lane A-row node offsets (fixed for whole K-loop)
    int ub[4], vb[4];
    #pragma unroll
    for (int fr = 0; fr < 4; ++fr) {
        int row = wy * 64 + fr * 16 + ln;
        int e = row < EPB ? row : 0;
        int2 p = ((const int2*)edges)[e];
        ub[fr] = p.x * 520;                   // u' section (w folded in)
        vb[fr] = p.y * 520 + 256;             // v' section
    }
    const short* bp = W2bf + (size_t)(wx * 64 + ln) * HH + q * 8;

    f32x4 zero = {0.f, 0.f, 0.f, 0.f};
    f32x4 acc[4][4];
    #pragma unroll
    for (int i = 0; i < 4; ++i)
        #pragma unroll
        for (int j = 0; j < 4; ++j) acc[i][j] = zero;

    __syncthreads();   // node data + acc init visible

    s16x8 bcur[4], bnxt[4];
    #pragma unroll
    for (int fc = 0; fc < 4; ++fc)
        bcur[fc] = *(const s16x8*)(bp + fc * 16 * HH);

    for (int kk = 0; kk < 8; ++kk) {
        if (kk < 7) {
            #pragma unroll
            for (int fc = 0; fc < 4; ++fc)
                bnxt[fc] = *(const s16x8*)(bp + fc * 16 * HH + (kk + 1) * 32);
        }
        // build A-fragments: h1 = leaky(u' + v') in bf16, per lane
        s16x8 af[4];
        #pragma unroll
        for (int fr = 0; fr < 4; ++fr) {
            s16x8 u8 = *(const s16x8*)&nodeL[ub[fr] + kk * 32 + q * 8];
            s16x8 v8 = *(const s16x8*)&nodeL[vb[fr] + kk * 32 + q * 8];
            const int* ui = (const int*)&u8;
            const int* vi = (const int*)&v8;
            int* oi = (int*)&af[fr];
            #pragma unroll
            for (int j = 0; j < 4; ++j) {
                int uu = ui[j], vv = vi[j];
                float s0 = __uint_as_float(((unsigned)uu) << 16) +
                           __uint_as_float(((unsigned)vv) << 16);
                float s1 = __uint_as_float((unsigned)uu & 0xffff0000u) +
                           __uint_as_float((unsigned)vv & 0xffff0000u);
                s0 = leaky(s0); s1 = leaky(s1);
                oi[j] = pk_bf16(s0, s1);
            }
        }
        #pragma unroll
        for (int fr = 0; fr < 4; ++fr)
            #pragma unroll
            for (int fc = 0; fc < 4; ++fc)
                acc[fr][fc] = __builtin_amdgcn_mfma_f32_16x16x32_bf16(af[fr], bcur[fc], acc[fr][fc], 0, 0, 0);
        #pragma unroll
        for (int fc = 0; fc < 4; ++fc) bcur[fc] = bnxt[fc];
    }

    // ---- fused epilogue: h2 = leaky(acc + b2); mu/sig head dots ----
    float pmu[4][4], psg[4][4];
    #pragma unroll
    for (int fr = 0; fr < 4; ++fr)
        #pragma unroll
        for (int rg = 0; rg < 4; ++rg) { pmu[fr][rg] = 0.f; psg[fr][rg] = 0.f; }

    #pragma unroll
    for (int fc = 0; fc < 4; ++fc) {
        int col = wx * 64 + fc * 16 + ln;
        float bb = lin2_b[col], mw = mu_w[col], sw = sig_w[col];
        #pragma unroll
        for (int fr = 0; fr < 4; ++fr)
            #pragma unroll
            for (int rg = 0; rg < 4; ++rg) {
                float h2 = leaky(acc[fr][fc][rg] + bb);
                pmu[fr][rg] += mw * h2;
                psg[fr][rg] += sw * h2;
            }
    }
    #pragma unroll
    for (int fr = 0; fr < 4; ++fr)
        #pragma unroll
        for (int rg = 0; rg < 4; ++rg) {
            float a = pmu[fr][rg], s2 = psg[fr][rg];
            #pragma unroll
            for (int off = 1; off < 16; off <<= 1) {
                a  += __shfl_xor(a, off);
                s2 += __shfl_xor(s2, off);
            }
            if (ln == 0) {
                int row = wy * 64 + fr * 16 + q * 4 + rg;
                atomicAdd(&mu_acc[row], a);
                atomicAdd(&sg_acc[row], s2);
            }
        }
    __syncthreads();

    if (t < EPB) {
        float mu = softplusf(mu_acc[t] + mu_b[0]);
        float sd = softplusf(sg_acc[t] + sig_b[0]);
        float z = noise[(size_t)b * EPB + t];
        out[(size_t)b * EPB + t] = mu + sd * z;
        atomicAdd(&lp_acc, -0.5f * z * z - logf(sd));
    }
    __syncthreads();
    if (t == 0) out[M2 + b] = lp_acc + LP_CONST;
}

// ---------------------------------------------------------------------------
extern "C" void kernel_launch(void* const* d_in, const int* in_sizes, int n_in,
                              void* d_out, int out_size, void* d_ws, size_t ws_size,
                              hipStream_t stream)
{
    const float* state  = (const float*)d_in[0];
    const float* conv_w = (const float*)d_in[1];
    const float* conv_b = (const float*)d_in[2];
    const float* lin1_w = (const float*)d_in[3];
    const float* lin1_b = (const float*)d_in[4];
    const float* lin2_w = (const float*)d_in[5];
    const float* lin2_b = (const float*)d_in[6];
    const float* mu_w   = (const float*)d_in[7];
    const float* mu_b   = (const float*)d_in[8];
    const float* sig_w  = (const float*)d_in[9];
    const float* sig_b  = (const float*)d_in[10];
    const float* noise  = (const float*)d_in[11];
    const int*   edges  = (const int*)d_in[13];
    float* out = (float*)d_out;

    char* ws = (char*)d_ws;
    float* wvec = (float*)ws;   ws += (size_t)NB * HH * 4;          // 2 MB
    short* UV   = (short*)ws;   ws += (size_t)NODES * 512 * 2;      // 28 MB
    short* W2bf = (short*)ws;   ws += 65536 * 2;
    short* W1bf = (short*)ws;   ws += 65536 * 2;
    float* cwT  = (float*)ws;   ws += 16384 * 4;
    float* w1sT = (float*)ws;   ws += 32768 * 4;

    prep_kernel<<<256, 256, 0, stream>>>(conv_w, lin1_w, lin2_w, W2bf, W1bf, cwT, w1sT);
    gw_kernel<<<NB / BPB, 256, 0, stream>>>(state, cwT, conv_b, w1sT, lin1_b, wvec);
    uv_gemm<<<dim3(NODES / 128, 2), 512, 0, stream>>>(state, W1bf, wvec, UV);
    edge_gemm<<<NB, 768, 0, stream>>>(UV, W2bf, lin2_b,
                                      mu_w, mu_b, sig_w, sig_b,
                                      noise, edges, out);
}